// Round 1
// baseline (164.217 us; speedup 1.0000x reference)
//
#include <hip/hip_runtime.h>

// TransfPropModule: per-edge (== per-point, since edge_index[0] == arange)
//   c = edge_index[1][p]
//   R_point[p] = R[c]                       (9 f32)
//   t_point[p] = t[c]                       (3 f32)
//   x_pred     = R[c] @ pos[p] + t[c]
//   x_out[p]   = x[p]*w[c] + x_pred*(1-w[c])
// Memory-bound: ~112 MB streamed reads + ~240 MB streamed writes; the
// R/t/w tables (<1 MB total) stay L2-resident.

__global__ void __launch_bounds__(256)
transf_prop_kernel(const float* __restrict__ x,
                   const float* __restrict__ pos,
                   const float* __restrict__ cw,
                   const float* __restrict__ Rm,
                   const float* __restrict__ tm,
                   const int*   __restrict__ cidx,
                   float* __restrict__ Rp,
                   float* __restrict__ tp,
                   float* __restrict__ xo,
                   int n)
{
    int p = blockIdx.x * blockDim.x + threadIdx.x;
    if (p >= n) return;

    int c = cidx[p];

    const float* Rc = Rm + (size_t)c * 9;
    float r00 = Rc[0], r01 = Rc[1], r02 = Rc[2];
    float r10 = Rc[3], r11 = Rc[4], r12 = Rc[5];
    float r20 = Rc[6], r21 = Rc[7], r22 = Rc[8];

    const float* tc = tm + (size_t)c * 3;
    float t0 = tc[0], t1 = tc[1], t2 = tc[2];

    float w = cw[c];

    const float* pp = pos + (size_t)p * 3;
    float p0 = pp[0], p1 = pp[1], p2 = pp[2];

    const float* xp = x + (size_t)p * 3;
    float x0 = xp[0], x1 = xp[1], x2 = xp[2];

    // x_pred = R @ pos + t
    float pr0 = fmaf(r00, p0, fmaf(r01, p1, fmaf(r02, p2, t0)));
    float pr1 = fmaf(r10, p0, fmaf(r11, p1, fmaf(r12, p2, t1)));
    float pr2 = fmaf(r20, p0, fmaf(r21, p1, fmaf(r22, p2, t2)));

    float omw = 1.0f - w;
    float o0 = x0 * w + pr0 * omw;
    float o1 = x1 * w + pr1 * omw;
    float o2 = x2 * w + pr2 * omw;

    float* Ro = Rp + (size_t)p * 9;
    Ro[0] = r00; Ro[1] = r01; Ro[2] = r02;
    Ro[3] = r10; Ro[4] = r11; Ro[5] = r12;
    Ro[6] = r20; Ro[7] = r21; Ro[8] = r22;

    float* to = tp + (size_t)p * 3;
    to[0] = t0; to[1] = t1; to[2] = t2;

    float* oo = xo + (size_t)p * 3;
    oo[0] = o0; oo[1] = o1; oo[2] = o2;
}

extern "C" void kernel_launch(void* const* d_in, const int* in_sizes, int n_in,
                              void* d_out, int out_size, void* d_ws, size_t ws_size,
                              hipStream_t stream) {
    const float* x   = (const float*)d_in[0];
    const float* pos = (const float*)d_in[1];
    // d_in[2] = batch (unused by reference)
    const float* cw  = (const float*)d_in[3];
    const float* Rm  = (const float*)d_in[4];
    const float* tm  = (const float*)d_in[5];
    const int*  edge = (const int*)d_in[6];

    const int n = in_sizes[0] / 3;           // N points
    const int* cidx = edge + n;              // edge_index row 1 = cluster idx

    float* out = (float*)d_out;
    float* Rp = out;                          // [N,3,3]
    float* tp = out + (size_t)n * 9;          // [N,3]
    float* xo = out + (size_t)n * 12;         // [N,3]

    const int block = 256;
    const int grid = (n + block - 1) / block;
    transf_prop_kernel<<<grid, block, 0, stream>>>(x, pos, cw, Rm, tm, cidx,
                                                   Rp, tp, xo, n);
}

// Round 2
// 78.177 us; speedup vs baseline: 2.1006x; 2.1006x over previous
//
#include <hip/hip_runtime.h>

// TransfPropModule — LDS-staged, fully coalesced version.
//   c = edge_index[1][p]
//   R_point[p] = R[c];  t_point[p] = t[c]
//   x_pred     = R[c] @ pos[p] + t[c]
//   x_out[p]   = x[p]*w[c] + x_pred*(1-w[c])
//
// Round-1 lesson: AoS per-thread access (9/3-float runs per lane) fragmented
// every global load/store across ~36 cache lines -> 1.7 TB/s. Fix: stage
// pos/x reads and all three outputs through LDS in flat output order, so
// every global access is lane-contiguous dwords.
//
// LDS/block: (768*2 + 2304 + 768 + 768) * 4 B = 21504 B -> 7 blocks/CU.

__global__ void __launch_bounds__(256)
transf_prop_kernel(const float* __restrict__ x,
                   const float* __restrict__ pos,
                   const float* __restrict__ cw,
                   const float* __restrict__ Rm,
                   const float* __restrict__ tm,
                   const int*   __restrict__ cidx,
                   float* __restrict__ Rp,
                   float* __restrict__ tp,
                   float* __restrict__ xo,
                   int n)
{
    __shared__ float s_pos[768];
    __shared__ float s_x[768];
    __shared__ float s_R[2304];
    __shared__ float s_t[768];
    __shared__ float s_o[768];

    const int t    = threadIdx.x;
    const int base = blockIdx.x * 256;
    const int m    = min(256, n - base);   // valid points in this block
    const int m3   = m * 3;
    const int m9   = m * 9;

    // ---- coalesced input staging (stride-1 dwords across lanes) ----
    const float* posb = pos + (size_t)base * 3;
    const float* xb   = x   + (size_t)base * 3;
    #pragma unroll
    for (int k = 0; k < 3; ++k) {
        int i = t + 256 * k;
        if (i < m3) {
            s_pos[i] = posb[i];
            s_x[i]   = xb[i];
        }
    }
    __syncthreads();

    // ---- per-point gather + compute, results staged to LDS in output order ----
    if (t < m) {
        const int c = cidx[base + t];

        const float* Rc = Rm + (size_t)c * 9;
        float r[9];
        #pragma unroll
        for (int j = 0; j < 9; ++j) r[j] = Rc[j];

        const float* tc = tm + (size_t)c * 3;
        const float t0 = tc[0], t1 = tc[1], t2 = tc[2];
        const float w  = cw[c];

        const float p0 = s_pos[t * 3 + 0];
        const float p1 = s_pos[t * 3 + 1];
        const float p2 = s_pos[t * 3 + 2];
        const float x0 = s_x[t * 3 + 0];
        const float x1 = s_x[t * 3 + 1];
        const float x2 = s_x[t * 3 + 2];

        const float pr0 = fmaf(r[0], p0, fmaf(r[1], p1, fmaf(r[2], p2, t0)));
        const float pr1 = fmaf(r[3], p0, fmaf(r[4], p1, fmaf(r[5], p2, t1)));
        const float pr2 = fmaf(r[6], p0, fmaf(r[7], p1, fmaf(r[8], p2, t2)));
        const float omw = 1.0f - w;

        #pragma unroll
        for (int j = 0; j < 9; ++j) s_R[t * 9 + j] = r[j];
        s_t[t * 3 + 0] = t0;
        s_t[t * 3 + 1] = t1;
        s_t[t * 3 + 2] = t2;
        s_o[t * 3 + 0] = fmaf(x0, w, pr0 * omw);
        s_o[t * 3 + 1] = fmaf(x1, w, pr1 * omw);
        s_o[t * 3 + 2] = fmaf(x2, w, pr2 * omw);
    }
    __syncthreads();

    // ---- coalesced writeback (stride-1, non-temporal: outputs never re-read) ----
    float* Rb = Rp + (size_t)base * 9;
    #pragma unroll
    for (int k = 0; k < 9; ++k) {
        int i = t + 256 * k;
        if (i < m9) __builtin_nontemporal_store(s_R[i], &Rb[i]);
    }
    float* tb = tp + (size_t)base * 3;
    float* ob = xo + (size_t)base * 3;
    #pragma unroll
    for (int k = 0; k < 3; ++k) {
        int i = t + 256 * k;
        if (i < m3) {
            __builtin_nontemporal_store(s_t[i], &tb[i]);
            __builtin_nontemporal_store(s_o[i], &ob[i]);
        }
    }
}

extern "C" void kernel_launch(void* const* d_in, const int* in_sizes, int n_in,
                              void* d_out, int out_size, void* d_ws, size_t ws_size,
                              hipStream_t stream) {
    const float* x   = (const float*)d_in[0];
    const float* pos = (const float*)d_in[1];
    // d_in[2] = batch (unused by reference)
    const float* cw  = (const float*)d_in[3];
    const float* Rm  = (const float*)d_in[4];
    const float* tm  = (const float*)d_in[5];
    const int*  edge = (const int*)d_in[6];

    const int n = in_sizes[0] / 3;           // N points
    const int* cidx = edge + n;              // edge_index row 1 = cluster idx

    float* out = (float*)d_out;
    float* Rp = out;                          // [N,3,3]
    float* tp = out + (size_t)n * 9;          // [N,3]
    float* xo = out + (size_t)n * 12;         // [N,3]

    const int block = 256;
    const int grid = (n + block - 1) / block;
    transf_prop_kernel<<<grid, block, 0, stream>>>(x, pos, cw, Rm, tm, cidx,
                                                   Rp, tp, xo, n);
}

// Round 3
// 77.211 us; speedup vs baseline: 2.1268x; 1.0125x over previous
//
#include <hip/hip_runtime.h>

// TransfPropModule — LDS-staged + float4-vectorized global traffic.
//   c = edge_index[1][p]
//   R_point[p] = R[c];  t_point[p] = t[c]
//   x_pred     = R[c] @ pos[p] + t[c]
//   x_out[p]   = x[p]*w[c] + x_pred*(1-w[c])
//
// Round-2 lesson: scalar dword streams ran at 3.9 TB/s; the 6.3 TB/s copy
// ceiling (m13) needs 16 B/lane. All streaming global accesses are now
// dwordx4; outputs are non-temporal so the 246 MB write stream doesn't
// evict the L3-resident inputs (FETCH was 61 MB < 112 MB streamed: L3 is
// serving ~half the reads — keep it that way).

typedef float f4 __attribute__((ext_vector_type(4)));

__global__ void __launch_bounds__(256)
transf_prop_kernel(const float* __restrict__ x,
                   const float* __restrict__ pos,
                   const float* __restrict__ cw,
                   const float* __restrict__ Rm,
                   const float* __restrict__ tm,
                   const int*   __restrict__ cidx,
                   float* __restrict__ Rp,
                   float* __restrict__ tp,
                   float* __restrict__ xo,
                   int n)
{
    __shared__ __align__(16) float s_pos[768];
    __shared__ __align__(16) float s_x[768];
    __shared__ __align__(16) float s_R[2304];
    __shared__ __align__(16) float s_t[768];
    __shared__ __align__(16) float s_o[768];

    const int t    = threadIdx.x;
    const int base = blockIdx.x * 256;

    if (base + 256 <= n) {
        // ---------- fast path: full block of 256 points ----------
        // gather index + R/t/w loads issued first (L2-resident, overlap staging)
        const int c = cidx[base + t];
        const float* Rc = Rm + (size_t)c * 9;
        float r[9];
        #pragma unroll
        for (int j = 0; j < 9; ++j) r[j] = Rc[j];
        const float* tc = tm + (size_t)c * 3;
        const float t0 = tc[0], t1 = tc[1], t2 = tc[2];
        const float w  = cw[c];

        // coalesced float4 staging of pos/x (768 floats = 192 vec4 each)
        const f4* pos4 = (const f4*)(pos + (size_t)base * 3);
        const f4* x4   = (const f4*)(x   + (size_t)base * 3);
        if (t < 192) {
            ((f4*)s_pos)[t] = pos4[t];
            ((f4*)s_x)[t]   = x4[t];
        }
        __syncthreads();

        const float p0 = s_pos[t * 3 + 0];
        const float p1 = s_pos[t * 3 + 1];
        const float p2 = s_pos[t * 3 + 2];
        const float x0 = s_x[t * 3 + 0];
        const float x1 = s_x[t * 3 + 1];
        const float x2 = s_x[t * 3 + 2];

        const float pr0 = fmaf(r[0], p0, fmaf(r[1], p1, fmaf(r[2], p2, t0)));
        const float pr1 = fmaf(r[3], p0, fmaf(r[4], p1, fmaf(r[5], p2, t1)));
        const float pr2 = fmaf(r[6], p0, fmaf(r[7], p1, fmaf(r[8], p2, t2)));
        const float omw = 1.0f - w;

        #pragma unroll
        for (int j = 0; j < 9; ++j) s_R[t * 9 + j] = r[j];
        s_t[t * 3 + 0] = t0;
        s_t[t * 3 + 1] = t1;
        s_t[t * 3 + 2] = t2;
        s_o[t * 3 + 0] = fmaf(x0, w, pr0 * omw);
        s_o[t * 3 + 1] = fmaf(x1, w, pr1 * omw);
        s_o[t * 3 + 2] = fmaf(x2, w, pr2 * omw);
        __syncthreads();

        // vectorized non-temporal writeback
        f4* Rb4 = (f4*)(Rp + (size_t)base * 9);        // 2304 f = 576 vec4
        const f4* sR4 = (const f4*)s_R;
        __builtin_nontemporal_store(sR4[t],       &Rb4[t]);
        __builtin_nontemporal_store(sR4[t + 256], &Rb4[t + 256]);
        if (t < 64)
            __builtin_nontemporal_store(sR4[t + 512], &Rb4[t + 512]);

        f4* tb4 = (f4*)(tp + (size_t)base * 3);        // 192 vec4
        f4* ob4 = (f4*)(xo + (size_t)base * 3);
        if (t < 192) {
            __builtin_nontemporal_store(((const f4*)s_t)[t], &tb4[t]);
            __builtin_nontemporal_store(((const f4*)s_o)[t], &ob4[t]);
        }
    } else {
        // ---------- generic tail path (unused when n % 256 == 0) ----------
        const int m  = n - base;
        const int m3 = m * 3, m9 = m * 9;
        const float* posb = pos + (size_t)base * 3;
        const float* xb   = x   + (size_t)base * 3;
        for (int k = 0; k < 3; ++k) {
            int i = t + 256 * k;
            if (i < m3) { s_pos[i] = posb[i]; s_x[i] = xb[i]; }
        }
        __syncthreads();
        if (t < m) {
            const int c = cidx[base + t];
            const float* Rc = Rm + (size_t)c * 9;
            float r[9];
            for (int j = 0; j < 9; ++j) r[j] = Rc[j];
            const float* tc = tm + (size_t)c * 3;
            const float t0 = tc[0], t1 = tc[1], t2 = tc[2];
            const float w  = cw[c];
            const float p0 = s_pos[t*3], p1 = s_pos[t*3+1], p2 = s_pos[t*3+2];
            const float x0 = s_x[t*3],   x1 = s_x[t*3+1],   x2 = s_x[t*3+2];
            const float pr0 = fmaf(r[0], p0, fmaf(r[1], p1, fmaf(r[2], p2, t0)));
            const float pr1 = fmaf(r[3], p0, fmaf(r[4], p1, fmaf(r[5], p2, t1)));
            const float pr2 = fmaf(r[6], p0, fmaf(r[7], p1, fmaf(r[8], p2, t2)));
            const float omw = 1.0f - w;
            for (int j = 0; j < 9; ++j) s_R[t * 9 + j] = r[j];
            s_t[t*3] = t0; s_t[t*3+1] = t1; s_t[t*3+2] = t2;
            s_o[t*3]   = fmaf(x0, w, pr0 * omw);
            s_o[t*3+1] = fmaf(x1, w, pr1 * omw);
            s_o[t*3+2] = fmaf(x2, w, pr2 * omw);
        }
        __syncthreads();
        float* Rb = Rp + (size_t)base * 9;
        for (int k = 0; k < 9; ++k) {
            int i = t + 256 * k;
            if (i < m9) __builtin_nontemporal_store(s_R[i], &Rb[i]);
        }
        float* tb = tp + (size_t)base * 3;
        float* ob = xo + (size_t)base * 3;
        for (int k = 0; k < 3; ++k) {
            int i = t + 256 * k;
            if (i < m3) {
                __builtin_nontemporal_store(s_t[i], &tb[i]);
                __builtin_nontemporal_store(s_o[i], &ob[i]);
            }
        }
    }
}

extern "C" void kernel_launch(void* const* d_in, const int* in_sizes, int n_in,
                              void* d_out, int out_size, void* d_ws, size_t ws_size,
                              hipStream_t stream) {
    const float* x   = (const float*)d_in[0];
    const float* pos = (const float*)d_in[1];
    // d_in[2] = batch (unused by reference)
    const float* cw  = (const float*)d_in[3];
    const float* Rm  = (const float*)d_in[4];
    const float* tm  = (const float*)d_in[5];
    const int*  edge = (const int*)d_in[6];

    const int n = in_sizes[0] / 3;           // N points
    const int* cidx = edge + n;              // edge_index row 1 = cluster idx

    float* out = (float*)d_out;
    float* Rp = out;                          // [N,3,3]
    float* tp = out + (size_t)n * 9;          // [N,3]
    float* xo = out + (size_t)n * 12;         // [N,3]

    const int block = 256;
    const int grid = (n + block - 1) / block;
    transf_prop_kernel<<<grid, block, 0, stream>>>(x, pos, cw, Rm, tm, cidx,
                                                   Rp, tp, xo, n);
}

// Round 4
// 63.250 us; speedup vs baseline: 2.5963x; 1.2207x over previous
//
#include <hip/hip_runtime.h>

// TransfPropModule — prepacked-gather version.
//
// Round-3 lesson: stream vectorization was neutral; the limiter is gather
// address divergence (13 scalar dword gathers/point -> ~832 L1 txn/wave).
// Fix: prepack [R|t|w] into 64 B-aligned 16-float rows in d_ws (1 MB,
// L2-resident); per-point gather becomes 4 aligned dwordx4 touching ONE
// cache line -> 256 txn/wave, under the ~49 us stream-BW floor.

typedef float f4 __attribute__((ext_vector_type(4)));

__global__ void __launch_bounds__(256)
prepack_kernel(const float* __restrict__ cw,
               const float* __restrict__ Rm,
               const float* __restrict__ tm,
               float* __restrict__ packed,
               int M)
{
    int i = blockIdx.x * 256 + threadIdx.x;   // element index into packed
    if (i >= M * 16) return;
    int r = i >> 4, j = i & 15;
    float v = 0.0f;
    if (j < 9)       v = Rm[r * 9 + j];
    else if (j < 12) v = tm[r * 3 + (j - 9)];
    else if (j == 12) v = cw[r];
    packed[i] = v;
}

__global__ void __launch_bounds__(256)
transf_prop_kernel(const float* __restrict__ x,
                   const float* __restrict__ pos,
                   const float* __restrict__ packed,
                   const int*   __restrict__ cidx,
                   float* __restrict__ Rp,
                   float* __restrict__ tp,
                   float* __restrict__ xo,
                   int n)
{
    __shared__ __align__(16) float s_pos[768];
    __shared__ __align__(16) float s_x[768];
    __shared__ __align__(16) float s_R[2304];
    __shared__ __align__(16) float s_t[768];
    __shared__ __align__(16) float s_o[768];

    const int t    = threadIdx.x;
    const int base = blockIdx.x * 256;

    if (base + 256 <= n) {
        // ---------- fast path: full block of 256 points ----------
        const int c = cidx[base + t];
        const f4* row = (const f4*)(packed + (size_t)c * 16);
        const f4 q0 = row[0];           // r0 r1 r2 r3
        const f4 q1 = row[1];           // r4 r5 r6 r7
        const f4 q2 = row[2];           // r8 t0 t1 t2
        const f4 q3 = row[3];           // w  -  -  -

        // coalesced float4 staging of pos/x (768 floats = 192 vec4 each)
        const f4* pos4 = (const f4*)(pos + (size_t)base * 3);
        const f4* x4   = (const f4*)(x   + (size_t)base * 3);
        if (t < 192) {
            ((f4*)s_pos)[t] = pos4[t];
            ((f4*)s_x)[t]   = x4[t];
        }
        __syncthreads();

        const float p0 = s_pos[t * 3 + 0];
        const float p1 = s_pos[t * 3 + 1];
        const float p2 = s_pos[t * 3 + 2];
        const float x0 = s_x[t * 3 + 0];
        const float x1 = s_x[t * 3 + 1];
        const float x2 = s_x[t * 3 + 2];

        const float pr0 = fmaf(q0.x, p0, fmaf(q0.y, p1, fmaf(q0.z, p2, q2.y)));
        const float pr1 = fmaf(q0.w, p0, fmaf(q1.x, p1, fmaf(q1.y, p2, q2.z)));
        const float pr2 = fmaf(q1.z, p0, fmaf(q1.w, p1, fmaf(q2.x, p2, q2.w)));
        const float w   = q3.x;
        const float omw = 1.0f - w;

        s_R[t * 9 + 0] = q0.x; s_R[t * 9 + 1] = q0.y; s_R[t * 9 + 2] = q0.z;
        s_R[t * 9 + 3] = q0.w; s_R[t * 9 + 4] = q1.x; s_R[t * 9 + 5] = q1.y;
        s_R[t * 9 + 6] = q1.z; s_R[t * 9 + 7] = q1.w; s_R[t * 9 + 8] = q2.x;
        s_t[t * 3 + 0] = q2.y;
        s_t[t * 3 + 1] = q2.z;
        s_t[t * 3 + 2] = q2.w;
        s_o[t * 3 + 0] = fmaf(x0, w, pr0 * omw);
        s_o[t * 3 + 1] = fmaf(x1, w, pr1 * omw);
        s_o[t * 3 + 2] = fmaf(x2, w, pr2 * omw);
        __syncthreads();

        // vectorized non-temporal writeback
        f4* Rb4 = (f4*)(Rp + (size_t)base * 9);        // 2304 f = 576 vec4
        const f4* sR4 = (const f4*)s_R;
        __builtin_nontemporal_store(sR4[t],       &Rb4[t]);
        __builtin_nontemporal_store(sR4[t + 256], &Rb4[t + 256]);
        if (t < 64)
            __builtin_nontemporal_store(sR4[t + 512], &Rb4[t + 512]);

        f4* tb4 = (f4*)(tp + (size_t)base * 3);        // 192 vec4
        f4* ob4 = (f4*)(xo + (size_t)base * 3);
        if (t < 192) {
            __builtin_nontemporal_store(((const f4*)s_t)[t], &tb4[t]);
            __builtin_nontemporal_store(((const f4*)s_o)[t], &ob4[t]);
        }
    } else {
        // ---------- generic tail path (unused when n % 256 == 0) ----------
        const int m  = n - base;
        const int m3 = m * 3, m9 = m * 9;
        const float* posb = pos + (size_t)base * 3;
        const float* xb   = x   + (size_t)base * 3;
        for (int k = 0; k < 3; ++k) {
            int i = t + 256 * k;
            if (i < m3) { s_pos[i] = posb[i]; s_x[i] = xb[i]; }
        }
        __syncthreads();
        if (t < m) {
            const int c = cidx[base + t];
            const float* row = packed + (size_t)c * 16;
            float r[9];
            for (int j = 0; j < 9; ++j) r[j] = row[j];
            const float t0 = row[9], t1 = row[10], t2 = row[11];
            const float w  = row[12];
            const float p0 = s_pos[t*3], p1 = s_pos[t*3+1], p2 = s_pos[t*3+2];
            const float x0 = s_x[t*3],   x1 = s_x[t*3+1],   x2 = s_x[t*3+2];
            const float pr0 = fmaf(r[0], p0, fmaf(r[1], p1, fmaf(r[2], p2, t0)));
            const float pr1 = fmaf(r[3], p0, fmaf(r[4], p1, fmaf(r[5], p2, t1)));
            const float pr2 = fmaf(r[6], p0, fmaf(r[7], p1, fmaf(r[8], p2, t2)));
            const float omw = 1.0f - w;
            for (int j = 0; j < 9; ++j) s_R[t * 9 + j] = r[j];
            s_t[t*3] = t0; s_t[t*3+1] = t1; s_t[t*3+2] = t2;
            s_o[t*3]   = fmaf(x0, w, pr0 * omw);
            s_o[t*3+1] = fmaf(x1, w, pr1 * omw);
            s_o[t*3+2] = fmaf(x2, w, pr2 * omw);
        }
        __syncthreads();
        float* Rb = Rp + (size_t)base * 9;
        for (int k = 0; k < 9; ++k) {
            int i = t + 256 * k;
            if (i < m9) __builtin_nontemporal_store(s_R[i], &Rb[i]);
        }
        float* tb = tp + (size_t)base * 3;
        float* ob = xo + (size_t)base * 3;
        for (int k = 0; k < 3; ++k) {
            int i = t + 256 * k;
            if (i < m3) {
                __builtin_nontemporal_store(s_t[i], &tb[i]);
                __builtin_nontemporal_store(s_o[i], &ob[i]);
            }
        }
    }
}

extern "C" void kernel_launch(void* const* d_in, const int* in_sizes, int n_in,
                              void* d_out, int out_size, void* d_ws, size_t ws_size,
                              hipStream_t stream) {
    const float* x   = (const float*)d_in[0];
    const float* pos = (const float*)d_in[1];
    // d_in[2] = batch (unused by reference)
    const float* cw  = (const float*)d_in[3];
    const float* Rm  = (const float*)d_in[4];
    const float* tm  = (const float*)d_in[5];
    const int*  edge = (const int*)d_in[6];

    const int n = in_sizes[0] / 3;           // N points
    const int M = in_sizes[3];               // clusters (cluster_weights is [M,1])
    const int* cidx = edge + n;              // edge_index row 1 = cluster idx

    float* out = (float*)d_out;
    float* Rp = out;                          // [N,3,3]
    float* tp = out + (size_t)n * 9;          // [N,3]
    float* xo = out + (size_t)n * 12;         // [N,3]

    float* packed = (float*)d_ws;             // [M,16] floats = 1 MB

    const int block = 256;
    const int pgrid = (M * 16 + block - 1) / block;
    prepack_kernel<<<pgrid, block, 0, stream>>>(cw, Rm, tm, packed, M);

    const int grid = (n + block - 1) / block;
    transf_prop_kernel<<<grid, block, 0, stream>>>(x, pos, packed, cidx,
                                                   Rp, tp, xo, n);
}